// Round 1
// baseline (275.131 us; speedup 1.0000x reference)
//
#include <hip/hip_runtime.h>
#include <hip/hip_bf16.h>
#include <float.h>

#define BB   32
#define PP   16384
#define NOBJ 50
#define NCLS 21
#define PBLK 64   // blocks of 256 priors per image (P/256)

// ---------------- workspace layout ----------------
// [0]       u64   bestprior[BB*NOBJ]   (12800 B) packed (iou_bits<<32)|(~p)
// [12800]   int   n_pos[BB]            (128 B)
// [12928]   double accum[3]            (24 B)  0:conf_pos 1:loc_sum 2:hard_neg
// [16384]   float overlap[BB*PP]       (2 MB)
// [+2MB]    int   objfor[BB*PP]        (2 MB)
// [+4MB]    float neg[BB*PP]           (2 MB)

__global__ void k_init(unsigned long long* __restrict__ bestprior,
                       int* __restrict__ n_pos, double* __restrict__ accum) {
    int i = blockIdx.x * 256 + threadIdx.x;
    if (i < BB * NOBJ) bestprior[i] = 0xFFFFFFFFull;  // iou=0, prior=0
    if (i < BB) n_pos[i] = 0;
    if (i < 3) accum[i] = 0.0;
}

__global__ __launch_bounds__(256) void k_overlap(
    const float* __restrict__ boxes, const float* __restrict__ priors,
    float* __restrict__ overlap, int* __restrict__ objfor,
    unsigned long long* __restrict__ bestprior)
{
#pragma clang fp contract(off)
    const int b  = (int)blockIdx.x >> 6;
    const int p0 = ((int)blockIdx.x & 63) << 8;
    const int t  = (int)threadIdx.x;
    const int p  = p0 + t;

    __shared__ float4 sbox[NOBJ];
    __shared__ float  sarea[NOBJ];
    __shared__ float  sio[NOBJ][257];   // padded: read lanes hit distinct banks

    if (t < NOBJ) {
        float4 bx = reinterpret_cast<const float4*>(boxes)[b * NOBJ + t];
        sbox[t]  = bx;
        sarea[t] = (bx.z - bx.x) * (bx.w - bx.y);
    }
    __syncthreads();

    float4 pc = reinterpret_cast<const float4*>(priors)[p];
    float hx = pc.z / 2.0f, hy = pc.w / 2.0f;
    float px0 = pc.x - hx, py0 = pc.y - hy;
    float px1 = pc.x + hx, py1 = pc.y + hy;
    float areab = (px1 - px0) * (py1 - py0);

    float best = -1.0f; int bestn = 0;
    for (int n = 0; n < NOBJ; ++n) {
        float4 bx = sbox[n];
        float ltx = fmaxf(bx.x, px0), lty = fmaxf(bx.y, py0);
        float rbx = fminf(bx.z, px1), rby = fminf(bx.w, py1);
        float dx = rbx - ltx; dx = dx > 0.0f ? dx : 0.0f;
        float dy = rby - lty; dy = dy > 0.0f ? dy : 0.0f;
        float inter = dx * dy;
        float iou = inter / ((sarea[n] + areab) - inter);
        sio[n][t] = iou;
        if (iou > best) { best = iou; bestn = n; }   // first-max wins (strict >)
    }
    overlap[b * PP + p] = best;
    objfor[b * PP + p]  = bestn;
    __syncthreads();

    if (t < NOBJ) {
        float bv = sio[t][0]; int bi = 0;
        for (int i = 1; i < 256; ++i) {
            float v = sio[t][i];
            if (v > bv) { bv = v; bi = i; }          // first-max within block
        }
        unsigned long long key =
            ((unsigned long long)__float_as_uint(bv) << 32) |
            (unsigned long long)(0xFFFFFFFFu - (unsigned)(p0 + bi));
        atomicMax(&bestprior[b * NOBJ + t], key);
    }
}

__global__ void k_force(const unsigned long long* __restrict__ bestprior,
                        float* __restrict__ overlap, int* __restrict__ objfor) {
    int b = (int)threadIdx.x;
    if (b >= BB) return;
    for (int n = 0; n < NOBJ; ++n) {                 // ascending n -> last wins
        unsigned long long pk = bestprior[b * NOBJ + n];
        int p = (int)(0xFFFFFFFFu - (unsigned)(pk & 0xFFFFFFFFull));
        objfor[b * PP + p]  = n;
        overlap[b * PP + p] = 1.0f;
    }
}

__global__ __launch_bounds__(256) void k_main(
    const float* __restrict__ locs, const float* __restrict__ scores,
    const float* __restrict__ boxes, const int* __restrict__ labels,
    const float* __restrict__ priors, const float* __restrict__ overlap,
    const int* __restrict__ objfor, float* __restrict__ neg,
    int* __restrict__ n_pos, double* __restrict__ accum)
{
#pragma clang fp contract(off)
    const int b   = (int)blockIdx.x >> 6;
    const int p   = (((int)blockIdx.x & 63) << 8) + (int)threadIdx.x;
    const int idx = b * PP + p;

    const int   n = objfor[idx];
    const float v = overlap[idx];
    int lbl = labels[b * NOBJ + n];
    if (v < 0.5f) lbl = 0;
    const bool pos = (lbl != 0);

    float locl1 = 0.0f;
    if (pos) {
        float4 bx = reinterpret_cast<const float4*>(boxes)[b * NOBJ + n];
        float4 pr = reinterpret_cast<const float4*>(priors)[p];
        float cx = (bx.x + bx.z) / 2.0f;
        float cy = (bx.y + bx.w) / 2.0f;
        float w  = bx.z - bx.x, h = bx.w - bx.y;
        float gx = (cx - pr.x) / (pr.z / 10.0f);
        float gy = (cy - pr.y) / (pr.w / 10.0f);
        float gw = logf(w / pr.z) * 5.0f;
        float gh = logf(h / pr.w) * 5.0f;
        float4 pl = reinterpret_cast<const float4*>(locs)[idx];
        locl1 = fabsf(pl.x - gx) + fabsf(pl.y - gy) +
                fabsf(pl.z - gw) + fabsf(pl.w - gh);
    }

    // cross-entropy via log-softmax over 21 classes (registers, static idx)
    const float* sc = scores + (size_t)idx * NCLS;
    float x[NCLS];
    float m = -FLT_MAX;
#pragma unroll
    for (int c = 0; c < NCLS; ++c) { x[c] = sc[c]; m = fmaxf(m, x[c]); }
    float tgt = 0.0f;
#pragma unroll
    for (int c = 0; c < NCLS; ++c) tgt = (c == lbl) ? x[c] : tgt;
    float s = 0.0f;
#pragma unroll
    for (int c = 0; c < NCLS; ++c) s += expf(x[c] - m);
    float ce = (logf(s) + m) - tgt;

    neg[idx] = pos ? 0.0f : ce;

    // wave reductions -> atomics
    float cp = pos ? ce : 0.0f;
    unsigned long long bal = __ballot(pos);
    float s1 = cp, s2 = locl1;
    for (int o = 32; o > 0; o >>= 1) {
        s1 += __shfl_down(s1, o, 64);
        s2 += __shfl_down(s2, o, 64);
    }
    if ((threadIdx.x & 63) == 0) {
        int cnt = (int)__popcll(bal);
        if (cnt) atomicAdd(&n_pos[b], cnt);
        if (s1 != 0.0f) atomicAdd(&accum[0], (double)s1);
        if (s2 != 0.0f) atomicAdd(&accum[1], (double)s2);
    }
}

// exact sum of top-K of neg[b,:] via 4x8-bit radix select (ce >= 0 so
// float bit pattern is order-preserving as uint)
__global__ __launch_bounds__(1024) void k_topk(
    const float* __restrict__ neg, const int* __restrict__ n_pos,
    double* __restrict__ accum)
{
    const int b = (int)blockIdx.x;
    const float* nv = neg + (size_t)b * PP;

    __shared__ unsigned int hist[256];
    __shared__ unsigned int s_bb, s_above;
    __shared__ float swave[16];

    long long K = 3LL * (long long)n_pos[b];
    if (K > PP) K = PP;
    unsigned remaining = (unsigned)K;
    unsigned prefix = 0, mask = 0;
    float mySum = 0.0f;

    for (int shift = 24; shift >= 0; shift -= 8) {
        if (threadIdx.x < 256) hist[threadIdx.x] = 0;
        __syncthreads();
        for (int i = threadIdx.x; i < PP; i += 1024) {
            unsigned u = __float_as_uint(nv[i]);
            if ((u & mask) == prefix) atomicAdd(&hist[(u >> shift) & 255u], 1u);
        }
        __syncthreads();
        if (threadIdx.x == 0) {
            unsigned cum = 0, bb = 0, above = 0;
            for (int bin = 255; bin >= 0; --bin) {
                unsigned c = hist[bin];
                if (cum + c >= remaining) { bb = (unsigned)bin; above = cum; break; }
                cum += c;
            }
            s_bb = bb; s_above = above;
        }
        __syncthreads();
        unsigned bb = s_bb;
        for (int i = threadIdx.x; i < PP; i += 1024) {
            unsigned u = __float_as_uint(nv[i]);
            if ((u & mask) == prefix && ((u >> shift) & 255u) > bb)
                mySum += __uint_as_float(u);
        }
        remaining -= s_above;
        prefix |= bb << shift;
        mask   |= 255u << shift;
        __syncthreads();
    }

    float s = mySum;
    for (int o = 32; o > 0; o >>= 1) s += __shfl_down(s, o, 64);
    int wid = (int)threadIdx.x >> 6;
    if ((threadIdx.x & 63) == 0) swave[wid] = s;
    __syncthreads();
    if (threadIdx.x == 0) {
        float tot = 0.0f;
        for (int w = 0; w < 16; ++w) tot += swave[w];
        if (remaining) tot += (float)remaining * __uint_as_float(prefix);
        atomicAdd(&accum[2], (double)tot);
    }
}

__global__ void k_final(const int* __restrict__ n_pos,
                        const double* __restrict__ accum,
                        float* __restrict__ out) {
    if (threadIdx.x == 0 && blockIdx.x == 0) {
        int tot = 0;
        for (int b = 0; b < BB; ++b) tot += n_pos[b];
        double npt  = (double)tot;
        double conf = (accum[0] + accum[2]) / npt;
        double loc  = accum[1] / (npt * 4.0);
        out[0] = (float)(conf + loc);
    }
}

extern "C" void kernel_launch(void* const* d_in, const int* in_sizes, int n_in,
                              void* d_out, int out_size, void* d_ws, size_t ws_size,
                              hipStream_t stream) {
    const float* locs   = (const float*)d_in[0];
    const float* scores = (const float*)d_in[1];
    const float* boxes  = (const float*)d_in[2];
    const int*   labels = (const int*)d_in[3];
    const float* priors = (const float*)d_in[4];

    char* ws = (char*)d_ws;
    unsigned long long* bestprior = (unsigned long long*)ws;
    int*    n_pos   = (int*)(ws + 12800);
    double* accum   = (double*)(ws + 12928);
    float*  overlap = (float*)(ws + 16384);
    int*    objfor  = (int*)(ws + 16384 + (size_t)BB * PP * 4);
    float*  neg     = (float*)(ws + 16384 + (size_t)BB * PP * 8);
    float*  out     = (float*)d_out;

    hipLaunchKernelGGL(k_init,    dim3(7),         dim3(256),  0, stream,
                       bestprior, n_pos, accum);
    hipLaunchKernelGGL(k_overlap, dim3(BB * PBLK), dim3(256),  0, stream,
                       boxes, priors, overlap, objfor, bestprior);
    hipLaunchKernelGGL(k_force,   dim3(1),         dim3(64),   0, stream,
                       bestprior, overlap, objfor);
    hipLaunchKernelGGL(k_main,    dim3(BB * PBLK), dim3(256),  0, stream,
                       locs, scores, boxes, labels, priors, overlap, objfor,
                       neg, n_pos, accum);
    hipLaunchKernelGGL(k_topk,    dim3(BB),        dim3(1024), 0, stream,
                       neg, n_pos, accum);
    hipLaunchKernelGGL(k_final,   dim3(1),         dim3(64),   0, stream,
                       n_pos, accum, out);
}